// Round 1
// baseline (967.057 us; speedup 1.0000x reference)
//
#include <hip/hip_runtime.h>

// ---------------- static graph constants (Traffic4cast 495x436 grid) -------
#define HH 495
#define WW 436
#define NN 215820          // HH*WW
#define NPOOL 54064        // 248*218 pooled nodes
#define PC 218             // pooled cols
#define EN 215384          // north/south edge count  (HH-1)*WW
#define EE 215325          // east/west edge count    HH*(WW-1)
#define KN 53846           // kept pooled edges north/south  247*218
#define KE 53816           // kept pooled edges east/west    248*217

// output layout offsets (in floats)
static constexpr size_t OFF_POS = (size_t)NPOOL * 128;           // 6,920,192
static constexpr size_t OFF_EIN = OFF_POS + (size_t)NPOOL * 2;   // 7,028,320
static constexpr size_t OFF_EIE = OFF_EIN + (size_t)KN * 2;      // 7,136,012
static constexpr size_t OFF_EIS = OFF_EIE + (size_t)KE * 2;      // 7,243,644
static constexpr size_t OFF_EIW = OFF_EIS + (size_t)KN * 2;      // 7,351,336
static constexpr size_t OFF_EFN = OFF_EIW + (size_t)KE * 2;      // 7,458,968
static constexpr size_t OFF_EFE = OFF_EFN + (size_t)KN * 32;     // 9,182,040
static constexpr size_t OFF_EFS = OFF_EFE + (size_t)KE * 32;     // 10,904,152
static constexpr size_t OFF_EFW = OFF_EFS + (size_t)KN * 32;     // 12,627,224
// total = 14,349,336 floats

// ---------------------------------------------------------------------------
// Kernel A: xq[q][n][j] = relu(x[n,:] @ W_emb[q][:,j]),  [N,128]x[128,32] x4
// 64-node tile per block, W in LDS. blockIdx.y = quadrant.
__global__ __launch_bounds__(256) void k_xq(const float* __restrict__ x,
                                            const float* __restrict__ W_emb,
                                            float* __restrict__ xq) {
  const int q  = blockIdx.y;
  const int n0 = blockIdx.x * 64;
  __shared__ float xs[64][129];   // +1 pad breaks stride-128 bank aliasing
  __shared__ float ws[128][32];
  const float* Wq = W_emb + q * 4096;
  for (int i = threadIdx.x; i < 4096; i += 256) ws[i >> 5][i & 31] = Wq[i];
  for (int i = threadIdx.x; i < 2048; i += 256) {
    int nl = i >> 5;
    int kk = (i & 31) << 2;
    int n  = n0 + nl; if (n >= NN) n = NN - 1;   // clamp; store is guarded
    const float4 v = *(const float4*)(x + (size_t)n * 128 + kk);
    xs[nl][kk] = v.x; xs[nl][kk + 1] = v.y; xs[nl][kk + 2] = v.z; xs[nl][kk + 3] = v.w;
  }
  __syncthreads();
  const int jg  = threadIdx.x & 7;   // output group of 4: j = jg*4..jg*4+3
  const int nl0 = threadIdx.x >> 3;  // 0..31, handles nodes nl0 and nl0+32
  float a00 = 0.f, a01 = 0.f, a02 = 0.f, a03 = 0.f;
  float a10 = 0.f, a11 = 0.f, a12 = 0.f, a13 = 0.f;
#pragma unroll 8
  for (int k = 0; k < 128; ++k) {
    const float  x0 = xs[nl0][k];
    const float  x1 = xs[nl0 + 32][k];
    const float4 w  = *(const float4*)&ws[k][jg << 2];
    a00 = fmaf(x0, w.x, a00); a01 = fmaf(x0, w.y, a01);
    a02 = fmaf(x0, w.z, a02); a03 = fmaf(x0, w.w, a03);
    a10 = fmaf(x1, w.x, a10); a11 = fmaf(x1, w.y, a11);
    a12 = fmaf(x1, w.z, a12); a13 = fmaf(x1, w.w, a13);
  }
  int n = n0 + nl0;
  if (n < NN) {
    float4 o;
    o.x = fmaxf(a00, 0.f); o.y = fmaxf(a01, 0.f);
    o.z = fmaxf(a02, 0.f); o.w = fmaxf(a03, 0.f);
    *(float4*)(xq + ((size_t)q * NN + n) * 32 + (jg << 2)) = o;
  }
  n += 32;
  if (n < NN) {
    float4 o;
    o.x = fmaxf(a10, 0.f); o.y = fmaxf(a11, 0.f);
    o.z = fmaxf(a12, 0.f); o.w = fmaxf(a13, 0.f);
    *(float4*)(xq + ((size_t)q * NN + n) * 32 + (jg << 2)) = o;
  }
}

// ---------------------------------------------------------------------------
// Kernel B: per edge e of direction q:
//   feat = relu([ef[e], xq[src], xq[dst]] @ W_edge[q])          (96x32)
//   agg[dst][q*32+j] = feat*0.25        (each node has <=1 in-edge per dir)
//   if edge's pooled group is kept: atomicMax into efeat output (feat >= 0)
// 32-thread slot per edge; W column held in 96 VGPRs (reused across edges).
// Slot's LDS row is touched only by its own wave -> no barrier needed.
__global__ __launch_bounds__(256) void k_edge(
    const int* __restrict__ ei_n, const int* __restrict__ ei_e,
    const int* __restrict__ ei_s, const int* __restrict__ ei_w,
    const float* __restrict__ ef_n, const float* __restrict__ ef_e,
    const float* __restrict__ ef_s, const float* __restrict__ ef_w,
    const float* __restrict__ xq, const float* __restrict__ W_edge,
    float* __restrict__ agg, float* __restrict__ out) {
  const int q = blockIdx.y;
  const int* ei; const float* ef; int E; float* efb;
  if (q == 0)      { ei = ei_n; ef = ef_n; E = EN; efb = out + OFF_EFN; }
  else if (q == 1) { ei = ei_e; ef = ef_e; E = EE; efb = out + OFF_EFE; }
  else if (q == 2) { ei = ei_s; ef = ef_s; E = EN; efb = out + OFF_EFS; }
  else             { ei = ei_w; ef = ef_w; E = EE; efb = out + OFF_EFW; }
  const int j    = threadIdx.x & 31;
  const int slot = threadIdx.x >> 5;
  const float* Wq = W_edge + q * 3072;
  float wcol[96];
#pragma unroll
  for (int k = 0; k < 96; ++k) wcol[k] = Wq[k * 32 + j];
  const float* xqq = xq + (size_t)q * NN * 32;
  __shared__ float ein[8][104];   // 104: 16B-aligned rows, bank-shifted
  const int e0 = blockIdx.x * 16;
#pragma unroll
  for (int rep = 0; rep < 2; ++rep) {
    const int e = e0 + rep * 8 + slot;
    if (e < E) {
      const int src = ei[2 * e];
      const int dst = ei[2 * e + 1];
      ein[slot][j]      = ef[(size_t)e * 32 + j];
      ein[slot][32 + j] = xqq[(size_t)src * 32 + j];
      ein[slot][64 + j] = xqq[(size_t)dst * 32 + j];
      // same-wave LDS RAW: ds ops complete in issue order within a wave
      float acc = 0.f;
#pragma unroll
      for (int kq = 0; kq < 24; ++kq) {
        const float4 a = *(const float4*)&ein[slot][kq << 2];
        acc = fmaf(a.x, wcol[4 * kq + 0], acc);
        acc = fmaf(a.y, wcol[4 * kq + 1], acc);
        acc = fmaf(a.z, wcol[4 * kq + 2], acc);
        acc = fmaf(a.w, wcol[4 * kq + 3], acc);
      }
      const float v = fmaxf(acc, 0.f);
      agg[(size_t)dst * 128 + q * 32 + j] = v * 0.25f;
      const int r = src / WW;
      const int c = src - r * WW;
      bool kept; int idx;
      if (q == 0)      { kept = (r & 1) == 0; idx = ((r >> 1) - 1) * 218 + (c >> 1); }
      else if (q == 1) { kept = (c & 1) == 1; idx = (r >> 1) * 217 + (c >> 1); }
      else if (q == 2) { kept = (r & 1) == 1; idx = (r >> 1) * 218 + (c >> 1); }
      else             { kept = (c & 1) == 0; idx = (r >> 1) * 217 + (c >> 1) - 1; }
      if (kept)
        atomicMax((int*)(efb + (size_t)idx * 32 + j), __float_as_int(v));
    }
  }
}

// ---------------------------------------------------------------------------
// Kernel C: x2[n] = relu([x[n] | agg[n]] @ W_node)  (256x128), then
// atomicMax into x_pooled (values >= 0, out zero-initialized).
// Thread (j = t&127, h = t>>7) holds W_node[h*128..h*128+127][j] in VGPRs.
// 4 nodes per iteration. NN % 4 == 0.
__global__ __launch_bounds__(256) void k_node(const float* __restrict__ x,
                                              const float* __restrict__ agg,
                                              const float* __restrict__ W_node,
                                              float* __restrict__ out) {
  const int j = threadIdx.x & 127;
  const int h = threadIdx.x >> 7;
  float w[128];
#pragma unroll
  for (int k = 0; k < 128; ++k) w[k] = W_node[(size_t)(h * 128 + k) * 128 + j];
  __shared__ float ins[4][256];
  __shared__ float part[4][128];
  const int nquads = NN / 4;   // 53955
  for (int quad = blockIdx.x; quad < nquads; quad += gridDim.x) {
    const int n0 = quad * 4;
    __syncthreads();   // protect ins/part reuse across iterations
#pragma unroll
    for (int i = 0; i < 4; ++i) {
      const int idx = threadIdx.x + i * 256;   // 0..1023
      const int nn  = idx >> 8;
      const int kk  = idx & 255;
      ins[nn][kk] = (kk < 128) ? x[(size_t)(n0 + nn) * 128 + kk]
                               : agg[(size_t)(n0 + nn) * 128 + (kk - 128)];
    }
    __syncthreads();
    float acc[4] = {0.f, 0.f, 0.f, 0.f};
#pragma unroll
    for (int kq = 0; kq < 32; ++kq) {
      const int kb = h * 128 + (kq << 2);
#pragma unroll
      for (int nn = 0; nn < 4; ++nn) {
        const float4 a = *(const float4*)&ins[nn][kb];
        acc[nn] = fmaf(a.x, w[4 * kq + 0], acc[nn]);
        acc[nn] = fmaf(a.y, w[4 * kq + 1], acc[nn]);
        acc[nn] = fmaf(a.z, w[4 * kq + 2], acc[nn]);
        acc[nn] = fmaf(a.w, w[4 * kq + 3], acc[nn]);
      }
    }
    if (h == 1) {
      part[0][j] = acc[0]; part[1][j] = acc[1];
      part[2][j] = acc[2]; part[3][j] = acc[3];
    }
    __syncthreads();
    if (h == 0) {
#pragma unroll
      for (int nn = 0; nn < 4; ++nn) {
        const float v = fmaxf(acc[nn] + part[nn][j], 0.f);
        const int n = n0 + nn;
        const int r = n / WW;
        const int c = n - r * WW;
        const int p = (r >> 1) * PC + (c >> 1);
        atomicMax((int*)(out + (size_t)p * 128 + j), __float_as_int(v));
      }
    }
  }
}

// ---------------------------------------------------------------------------
// Kernel D: closed-form new_pos + pooled edge indices (written as float).
__global__ __launch_bounds__(256) void k_misc(float* __restrict__ out) {
  int u = blockIdx.x * 256 + threadIdx.x;
  if (u < NPOOL * 2) {
    const int p  = u >> 1;
    const int pr = p / PC;
    const int pc = p - pr * PC;
    out[OFF_POS + u] = (float)((u & 1) ? pc : pr);
    return;
  }
  u -= NPOOL * 2;
  if (u < KN * 2) {   // north: kept i -> src=(i/218+1)*218+i%218, dst=src-218
    const int e  = u >> 1;
    const int kr = e / PC + 1;
    const int pc = e - (kr - 1) * PC;
    const int s  = kr * PC + pc;
    out[OFF_EIN + u] = (float)((u & 1) ? (s - PC) : s);
    return;
  }
  u -= KN * 2;
  if (u < KE * 2) {   // east: src=pr*218+j, dst=src+1
    const int e  = u >> 1;
    const int pr = e / 217;
    const int jj = e - pr * 217;
    const int s  = pr * PC + jj;
    out[OFF_EIE + u] = (float)((u & 1) ? (s + 1) : s);
    return;
  }
  u -= KE * 2;
  if (u < KN * 2) {   // south: src=k*218+pc, dst=src+218
    const int e  = u >> 1;
    const int k  = e / PC;
    const int pc = e - k * PC;
    const int s  = k * PC + pc;
    out[OFF_EIS + u] = (float)((u & 1) ? (s + PC) : s);
    return;
  }
  u -= KN * 2;
  if (u < KE * 2) {   // west: src=pr*218+j+1, dst=src-1
    const int e  = u >> 1;
    const int pr = e / 217;
    const int jj = e - pr * 217;
    const int s  = pr * PC + jj + 1;
    out[OFF_EIW + u] = (float)((u & 1) ? (s - 1) : s);
  }
}

// ---------------------------------------------------------------------------
extern "C" void kernel_launch(void* const* d_in, const int* in_sizes, int n_in,
                              void* d_out, int out_size, void* d_ws, size_t ws_size,
                              hipStream_t stream) {
  const float* x      = (const float*)d_in[0];
  const int*   ei_n   = (const int*)d_in[2];
  const int*   ei_e   = (const int*)d_in[3];
  const int*   ei_s   = (const int*)d_in[4];
  const int*   ei_w   = (const int*)d_in[5];
  const float* ef_n   = (const float*)d_in[6];
  const float* ef_e   = (const float*)d_in[7];
  const float* ef_s   = (const float*)d_in[8];
  const float* ef_w   = (const float*)d_in[9];
  const float* W_emb  = (const float*)d_in[10];
  const float* W_edge = (const float*)d_in[11];
  const float* W_node = (const float*)d_in[12];
  float* out = (float*)d_out;

  // workspace: xq [4][N][32] then agg [N][128]  (both N*128 floats)
  float* xq  = (float*)d_ws;
  float* agg = xq + (size_t)NN * 128;

  // zero-init: out (atomicMax identity for >=0 values), agg (missing edges)
  hipMemsetAsync(d_out, 0, (size_t)out_size * sizeof(float), stream);
  hipMemsetAsync(agg, 0, (size_t)NN * 128 * sizeof(float), stream);

  k_xq<<<dim3((NN + 63) / 64, 4), 256, 0, stream>>>(x, W_emb, xq);
  k_edge<<<dim3((EN + 15) / 16, 4), 256, 0, stream>>>(
      ei_n, ei_e, ei_s, ei_w, ef_n, ef_e, ef_s, ef_w, xq, W_edge, agg, out);
  k_node<<<dim3(2048), 256, 0, stream>>>(x, agg, W_node, out);

  const int misc_total = NPOOL * 2 + 2 * (KN * 2 + KE * 2);
  k_misc<<<dim3((misc_total + 255) / 256), 256, 0, stream>>>(out);
}